// Round 1
// baseline (175.543 us; speedup 1.0000x reference)
//
#include <hip/hip_runtime.h>

typedef _Float16 f16;
typedef _Float16 f16x4 __attribute__((ext_vector_type(4)));
typedef _Float16 f16x8 __attribute__((ext_vector_type(8)));
typedef float f32x4 __attribute__((ext_vector_type(4)));

// async global->LDS, 16B per lane; LDS dest = wave-uniform base + lane*16
#define LOADLDS16(gp, lp)                                                     \
  __builtin_amdgcn_global_load_lds(                                           \
      (const __attribute__((address_space(1))) void*)(gp),                    \
      (__attribute__((address_space(3))) void*)(lp), 16, 0, 0)

// ---------------------------------------------------------------------------
// Elementwise cast f32 -> f16 (vectorized)
// ---------------------------------------------------------------------------
__global__ __launch_bounds__(256) void k_cast(const float* __restrict__ x,
                                              f16* __restrict__ y, int n4) {
  int i = blockIdx.x * 256 + threadIdx.x;
  if (i >= n4) return;
  float4 v = reinterpret_cast<const float4*>(x)[i];
  f16x4 o;
  o[0] = (f16)v.x; o[1] = (f16)v.y; o[2] = (f16)v.z; o[3] = (f16)v.w;
  reinterpret_cast<f16x4*>(y)[i] = o;
}

// ---------------------------------------------------------------------------
// Cast + transpose weights: W[1024][1024] f32 -> Wt[N][K] f16  (Wt[n][k]=W[k][n])
// ---------------------------------------------------------------------------
__global__ __launch_bounds__(256) void k_castw_t(
    const float* __restrict__ w0, const float* __restrict__ w1,
    const float* __restrict__ w2, const float* __restrict__ w3,
    f16* __restrict__ o0, f16* __restrict__ o1, f16* __restrict__ o2,
    f16* __restrict__ o3) {
  const float* W;
  f16* O;
  switch (blockIdx.z) {
    case 0: W = w0; O = o0; break;
    case 1: W = w1; O = o1; break;
    case 2: W = w2; O = o2; break;
    default: W = w3; O = o3; break;
  }
  __shared__ f16 T[64][72];  // [col-in-tile][row-in-tile], padded
  const int tid = threadIdx.x;
  const int r0 = blockIdx.y * 64, c0 = blockIdx.x * 64;
#pragma unroll
  for (int i = 0; i < 4; ++i) {
    int c = i * 256 + tid;
    int row = c >> 4, col = (c & 15) * 4;
    float4 v = *reinterpret_cast<const float4*>(W + (size_t)(r0 + row) * 1024 + c0 + col);
    T[col + 0][row] = (f16)v.x;
    T[col + 1][row] = (f16)v.y;
    T[col + 2][row] = (f16)v.z;
    T[col + 3][row] = (f16)v.w;
  }
  __syncthreads();
#pragma unroll
  for (int i = 0; i < 2; ++i) {
    int c = i * 256 + tid;
    int cc = c >> 3, ro = (c & 7) * 8;
    f16x8 v;
#pragma unroll
    for (int j = 0; j < 8; ++j) v[j] = T[cc][ro + j];
    *reinterpret_cast<f16x8*>(O + (size_t)(c0 + cc) * 1024 + r0 + ro) = v;
  }
}

// ---------------------------------------------------------------------------
// GEMM: C[M,N] = A[M,K] @ Bt[N,K]^T, f16 in, f32 accum.
// BM=64, BN=128, BK=64; 256 threads = 4 waves (2x2), wave tile 32x64.
// EPI 0: plain f32 [M][N].  EPI 1: f16 in [b*16+h][s][64] layout (rows=(b,s), cols=(h,dh)).
// ---------------------------------------------------------------------------
template <int EPI>
__global__ __launch_bounds__(256) void k_gemm(const f16* __restrict__ A,
                                              const f16* __restrict__ Bt,
                                              void* __restrict__ out, int M,
                                              int N, int K) {
  __shared__ f16 As[64 * 64];    // 8 KB
  __shared__ f16 Bs[128 * 64];   // 16 KB
  const int tid = threadIdx.x;
  const int w = tid >> 6, l = tid & 63;
  const int lr = l & 15, lq = l >> 4;
  const int m0 = blockIdx.y * 64, n0 = blockIdx.x * 128;
  const int wr = (w >> 1) * 32, wc = (w & 1) * 64;
  f32x4 acc[2][4] = {};
  for (int kt = 0; kt < K; kt += 64) {
    // stage A: 512 x 16B chunks (2 rounds), B: 1024 chunks (4 rounds)
#pragma unroll
    for (int i = 0; i < 2; ++i) {
      int c = (i * 4 + w) * 64 + l;
      LOADLDS16(A + (size_t)(m0 + (c >> 3)) * K + kt + (c & 7) * 8,
                As + (size_t)(i * 4 + w) * 512);
    }
#pragma unroll
    for (int i = 0; i < 4; ++i) {
      int c = (i * 4 + w) * 64 + l;
      LOADLDS16(Bt + (size_t)(n0 + (c >> 3)) * K + kt + (c & 7) * 8,
                Bs + (size_t)(i * 4 + w) * 512);
    }
    __syncthreads();
#pragma unroll
    for (int kk = 0; kk < 2; ++kk) {
      f16x8 af[2], bf[4];
#pragma unroll
      for (int m = 0; m < 2; ++m)
        af[m] = *reinterpret_cast<const f16x8*>(As + (wr + m * 16 + lr) * 64 + kk * 32 + lq * 8);
#pragma unroll
      for (int n = 0; n < 4; ++n)
        bf[n] = *reinterpret_cast<const f16x8*>(Bs + (wc + n * 16 + lr) * 64 + kk * 32 + lq * 8);
#pragma unroll
      for (int m = 0; m < 2; ++m)
#pragma unroll
        for (int n = 0; n < 4; ++n)
          acc[m][n] = __builtin_amdgcn_mfma_f32_16x16x32_f16(af[m], bf[n], acc[m][n], 0, 0, 0);
    }
    __syncthreads();
  }
#pragma unroll
  for (int m = 0; m < 2; ++m)
#pragma unroll
    for (int n = 0; n < 4; ++n)
#pragma unroll
      for (int r = 0; r < 4; ++r) {
        int row = m0 + wr + m * 16 + lq * 4 + r;
        int col = n0 + wc + n * 16 + lr;
        if (EPI == 0) {
          reinterpret_cast<float*>(out)[(size_t)row * N + col] = acc[m][n][r];
        } else {
          int b = row >> 10, s = row & 1023, h = col >> 6, dh = col & 63;
          reinterpret_cast<f16*>(out)[(((size_t)(b * 16 + h)) * 1024 + s) * 64 + dh] =
              (f16)acc[m][n][r];
        }
      }
}

// ---------------------------------------------------------------------------
// V transpose per head: vb[bh][1024][64] -> vtb[bh][64][1024]
// ---------------------------------------------------------------------------
__global__ __launch_bounds__(256) void k_vtrans(const f16* __restrict__ vb,
                                                f16* __restrict__ vtb) {
  const int bh = blockIdx.y, s0 = blockIdx.x * 64;
  __shared__ f16 T[64][72];  // [dh][sk]
  const int tid = threadIdx.x;
  const f16* src = vb + (size_t)bh * 1024 * 64;
#pragma unroll
  for (int i = 0; i < 2; ++i) {
    int c = i * 256 + tid;
    int row = c >> 3, co = (c & 7) * 8;
    f16x8 v = *reinterpret_cast<const f16x8*>(src + (size_t)(s0 + row) * 64 + co);
#pragma unroll
    for (int j = 0; j < 8; ++j) T[co + j][row] = v[j];
  }
  __syncthreads();
  f16* dst = vtb + (size_t)bh * 64 * 1024;
#pragma unroll
  for (int i = 0; i < 2; ++i) {
    int c = i * 256 + tid;
    int dh = c >> 3, so = (c & 7) * 8;
    f16x8 v;
#pragma unroll
    for (int j = 0; j < 8; ++j) v[j] = T[dh][so + j];
    *reinterpret_cast<f16x8*>(dst + (size_t)dh * 1024 + s0 + so) = v;
  }
}

// ---------------------------------------------------------------------------
// Fused flash attention (T5: scores = QK^T + bias, no 1/sqrt scale).
// Block: 4 waves x 16 q-rows (QBLK=64); KV tiles of 64; online softmax in f32.
// gid = qt*64 + h*4 + b  (b innermost so batches sharing a bias tile co-run).
// ---------------------------------------------------------------------------
__global__ __launch_bounds__(256) void k_attn(const f16* __restrict__ qb,
                                              const f16* __restrict__ kb,
                                              const f16* __restrict__ vtb,
                                              const float* __restrict__ bias,
                                              f16* __restrict__ ctx) {
  const int gid = blockIdx.x;
  const int b = gid & 3, h = (gid >> 2) & 15, qt = gid >> 6;
  const int bh = b * 16 + h;
  const int q0 = qt * 64;
  const int tid = threadIdx.x, w = tid >> 6, l = tid & 63;
  const int lr = l & 15, lq = l >> 4;
  __shared__ f16 Ks[64][72];      // [kv][dh], +8 pad -> 2-way banks (free)
  __shared__ f16 Vs[64][72];      // [dh][kv]
  __shared__ f16 Ps[4][16][72];   // per-wave P round-trip [qrow][kv]

  const f16* qp = qb + ((size_t)bh * 1024 + q0 + w * 16 + lr) * 64 + lq * 8;
  f16x8 qf0 = *reinterpret_cast<const f16x8*>(qp);
  f16x8 qf1 = *reinterpret_cast<const f16x8*>(qp + 32);

  f32x4 O[4] = {};
  float mrun[4], lrun[4];
#pragma unroll
  for (int r = 0; r < 4; ++r) { mrun[r] = -3.0e38f; lrun[r] = 0.f; }

  const f16* kbase = kb + (size_t)bh * 1024 * 64;
  const f16* vbase = vtb + (size_t)bh * 64 * 1024;
  const float* bbase = bias + ((size_t)h * 1024 + q0 + w * 16) * 1024;

  for (int kv0 = 0; kv0 < 1024; kv0 += 64) {
    // ---- stage K tile [kv][dh] and V^T tile [dh][kv] (reg-staged, padded) ----
#pragma unroll
    for (int i = 0; i < 2; ++i) {
      int c = i * 256 + tid;
      int row = c >> 3, co = (c & 7) * 8;
      *reinterpret_cast<f16x8*>(&Ks[row][co]) =
          *reinterpret_cast<const f16x8*>(kbase + (size_t)(kv0 + row) * 64 + co);
      *reinterpret_cast<f16x8*>(&Vs[row][co]) =
          *reinterpret_cast<const f16x8*>(vbase + (size_t)row * 1024 + kv0 + co);
    }
    __syncthreads();

    // ---- S = Q K^T  (rows: lq*4+r, cols: c*16+lr) ----
    f32x4 S[4] = {};
#pragma unroll
    for (int c = 0; c < 4; ++c) {
      f16x8 kf0 = *reinterpret_cast<const f16x8*>(&Ks[c * 16 + lr][lq * 8]);
      f16x8 kf1 = *reinterpret_cast<const f16x8*>(&Ks[c * 16 + lr][32 + lq * 8]);
      S[c] = __builtin_amdgcn_mfma_f32_16x16x32_f16(qf0, kf0, S[c], 0, 0, 0);
      S[c] = __builtin_amdgcn_mfma_f32_16x16x32_f16(qf1, kf1, S[c], 0, 0, 0);
    }

    // ---- + position bias (f32, straight from global; batches share -> L2) ----
    const float* bp = bbase + kv0;
#pragma unroll
    for (int c = 0; c < 4; ++c)
#pragma unroll
      for (int r = 0; r < 4; ++r)
        S[c][r] += bp[(size_t)(lq * 4 + r) * 1024 + c * 16 + lr];

    // ---- online softmax (row = lq*4+r; reduce over 16 lanes of lr) ----
    float tmax[4];
#pragma unroll
    for (int r = 0; r < 4; ++r)
      tmax[r] = fmaxf(fmaxf(S[0][r], S[1][r]), fmaxf(S[2][r], S[3][r]));
#pragma unroll
    for (int msk = 1; msk <= 8; msk <<= 1)
#pragma unroll
      for (int r = 0; r < 4; ++r)
        tmax[r] = fmaxf(tmax[r], __shfl_xor(tmax[r], msk, 64));
    float scale[4], rsum[4];
#pragma unroll
    for (int r = 0; r < 4; ++r) {
      float mnew = fmaxf(mrun[r], tmax[r]);
      scale[r] = __expf(mrun[r] - mnew);
      mrun[r] = mnew;
      rsum[r] = 0.f;
    }
#pragma unroll
    for (int c = 0; c < 4; ++c)
#pragma unroll
      for (int r = 0; r < 4; ++r) {
        float p = __expf(S[c][r] - mrun[r]);
        S[c][r] = p;
        rsum[r] += p;
      }
#pragma unroll
    for (int msk = 1; msk <= 8; msk <<= 1)
#pragma unroll
      for (int r = 0; r < 4; ++r) rsum[r] += __shfl_xor(rsum[r], msk, 64);
#pragma unroll
    for (int r = 0; r < 4; ++r) lrun[r] = lrun[r] * scale[r] + rsum[r];

    // ---- rescale O, spill P (C-layout) to LDS for A-fragment reload ----
#pragma unroll
    for (int c = 0; c < 4; ++c)
#pragma unroll
      for (int r = 0; r < 4; ++r) {
        O[c][r] *= scale[r];
        Ps[w][lq * 4 + r][c * 16 + lr] = (f16)S[c][r];
      }
    __syncthreads();

    // ---- O += P @ V ----
    f16x8 pa0 = *reinterpret_cast<const f16x8*>(&Ps[w][lr][lq * 8]);
    f16x8 pa1 = *reinterpret_cast<const f16x8*>(&Ps[w][lr][32 + lq * 8]);
#pragma unroll
    for (int c = 0; c < 4; ++c) {
      f16x8 vf0 = *reinterpret_cast<const f16x8*>(&Vs[c * 16 + lr][lq * 8]);
      f16x8 vf1 = *reinterpret_cast<const f16x8*>(&Vs[c * 16 + lr][32 + lq * 8]);
      O[c] = __builtin_amdgcn_mfma_f32_16x16x32_f16(pa0, vf0, O[c], 0, 0, 0);
      O[c] = __builtin_amdgcn_mfma_f32_16x16x32_f16(pa1, vf1, O[c], 0, 0, 0);
    }
    __syncthreads();
  }

  // ---- epilogue: ctx[b][q][h*64+dh] f16 ----
#pragma unroll
  for (int c = 0; c < 4; ++c)
#pragma unroll
    for (int r = 0; r < 4; ++r) {
      float o = O[c][r] / lrun[r];
      int row = q0 + w * 16 + lq * 4 + r;
      ctx[((size_t)b * 1024 + row) * 1024 + h * 64 + c * 16 + lr] = (f16)o;
    }
}

// ---------------------------------------------------------------------------
extern "C" void kernel_launch(void* const* d_in, const int* in_sizes, int n_in,
                              void* d_out, int out_size, void* d_ws,
                              size_t ws_size, hipStream_t stream) {
  const float* input_ids = (const float*)d_in[0];
  const float* enc = (const float*)d_in[1];
  const float* bias = (const float*)d_in[2];
  const float* Wq = (const float*)d_in[3];
  const float* Wk = (const float*)d_in[4];
  const float* Wv = (const float*)d_in[5];
  const float* Wo = (const float*)d_in[6];

  char* ws = (char*)d_ws;
  const size_t MB = 1024 * 1024;
  // layout (48 MB total), with dead-buffer reuse:
  f16* Xq  = (f16*)(ws + 0 * MB);   // 8 MB; dead after Q-proj -> reused as ctx
  f16* Xkv = (f16*)(ws + 8 * MB);   // 8 MB; dead after V-proj -> reused as vtb
  f16* Wqt = (f16*)(ws + 16 * MB);  // 2 MB each
  f16* Wkt = (f16*)(ws + 18 * MB);
  f16* Wvt = (f16*)(ws + 20 * MB);
  f16* Wot = (f16*)(ws + 22 * MB);
  f16* qbuf = (f16*)(ws + 24 * MB); // 8 MB [bh][s][dh]
  f16* kbuf = (f16*)(ws + 32 * MB);
  f16* vbuf = (f16*)(ws + 40 * MB);
  f16* vtb = Xkv;   // [bh][dh][sk]
  f16* ctxb = Xq;   // [4096][1024]

  k_cast<<<4096, 256, 0, stream>>>(input_ids, Xq, 1048576);
  k_cast<<<4096, 256, 0, stream>>>(enc, Xkv, 1048576);
  k_castw_t<<<dim3(16, 16, 4), 256, 0, stream>>>(Wq, Wk, Wv, Wo, Wqt, Wkt, Wvt, Wot);

  k_gemm<1><<<dim3(8, 64), 256, 0, stream>>>(Xq, Wqt, (void*)qbuf, 4096, 1024, 1024);
  k_gemm<1><<<dim3(8, 64), 256, 0, stream>>>(Xkv, Wkt, (void*)kbuf, 4096, 1024, 1024);
  k_gemm<1><<<dim3(8, 64), 256, 0, stream>>>(Xkv, Wvt, (void*)vbuf, 4096, 1024, 1024);

  k_vtrans<<<dim3(16, 64), 256, 0, stream>>>(vbuf, vtb);

  k_attn<<<1024, 256, 0, stream>>>(qbuf, kbuf, vtb, bias, ctxb);

  k_gemm<0><<<dim3(8, 64), 256, 0, stream>>>(ctxb, Wot, d_out, 4096, 1024, 1024);
}

// Round 2
// 169.823 us; speedup vs baseline: 1.0337x; 1.0337x over previous
//
#include <hip/hip_runtime.h>

typedef _Float16 f16;
typedef _Float16 f16x4 __attribute__((ext_vector_type(4)));
typedef _Float16 f16x8 __attribute__((ext_vector_type(8)));
typedef float f32x4 __attribute__((ext_vector_type(4)));

// async global->LDS, 16B per lane; LDS dest = wave-uniform base + lane*16
#define LOADLDS16(gp, lp)                                                     \
  __builtin_amdgcn_global_load_lds(                                           \
      (const __attribute__((address_space(1))) void*)(gp),                    \
      (__attribute__((address_space(3))) void*)(lp), 16, 0, 0)

// ---------------------------------------------------------------------------
// Elementwise cast f32 -> f16 (vectorized)
// ---------------------------------------------------------------------------
__global__ __launch_bounds__(256) void k_cast(const float* __restrict__ x,
                                              f16* __restrict__ y, int n4) {
  int i = blockIdx.x * 256 + threadIdx.x;
  if (i >= n4) return;
  float4 v = reinterpret_cast<const float4*>(x)[i];
  f16x4 o;
  o[0] = (f16)v.x; o[1] = (f16)v.y; o[2] = (f16)v.z; o[3] = (f16)v.w;
  reinterpret_cast<f16x4*>(y)[i] = o;
}

// ---------------------------------------------------------------------------
// Cast + transpose weights: W[1024][1024] f32 -> Wt[N][K] f16  (Wt[n][k]=W[k][n])
// ---------------------------------------------------------------------------
__global__ __launch_bounds__(256) void k_castw_t(
    const float* __restrict__ w0, const float* __restrict__ w1,
    const float* __restrict__ w2, const float* __restrict__ w3,
    f16* __restrict__ o0, f16* __restrict__ o1, f16* __restrict__ o2,
    f16* __restrict__ o3) {
  const float* W;
  f16* O;
  switch (blockIdx.z) {
    case 0: W = w0; O = o0; break;
    case 1: W = w1; O = o1; break;
    case 2: W = w2; O = o2; break;
    default: W = w3; O = o3; break;
  }
  __shared__ f16 T[64][72];  // [col-in-tile][row-in-tile], padded
  const int tid = threadIdx.x;
  const int r0 = blockIdx.y * 64, c0 = blockIdx.x * 64;
#pragma unroll
  for (int i = 0; i < 4; ++i) {
    int c = i * 256 + tid;
    int row = c >> 4, col = (c & 15) * 4;
    float4 v = *reinterpret_cast<const float4*>(W + (size_t)(r0 + row) * 1024 + c0 + col);
    T[col + 0][row] = (f16)v.x;
    T[col + 1][row] = (f16)v.y;
    T[col + 2][row] = (f16)v.z;
    T[col + 3][row] = (f16)v.w;
  }
  __syncthreads();
#pragma unroll
  for (int i = 0; i < 2; ++i) {
    int c = i * 256 + tid;
    int cc = c >> 3, ro = (c & 7) * 8;
    f16x8 v;
#pragma unroll
    for (int j = 0; j < 8; ++j) v[j] = T[cc][ro + j];
    *reinterpret_cast<f16x8*>(O + (size_t)(c0 + cc) * 1024 + r0 + ro) = v;
  }
}

// ---------------------------------------------------------------------------
// GEMM: C[M,N] = A[M,K] @ Bt[N,K]^T, f16 in, f32 accum.
// BM=64, BN=128, BK=64; 256 threads = 4 waves (2x2), wave tile 32x64.
// EPI 0: plain f32 [M][N].
// EPI 1: f16 head-layout; supports fused N=2048 (col>>10 selects K vs V plane
//        of 4M f16 elems each): out[plane*4M + ((b*16+h)*1024+s)*64+dh]
// ---------------------------------------------------------------------------
template <int EPI>
__global__ __launch_bounds__(256) void k_gemm(const f16* __restrict__ A,
                                              const f16* __restrict__ Bt,
                                              void* __restrict__ out, int M,
                                              int N, int K) {
  __shared__ f16 As[64 * 64];    // 8 KB
  __shared__ f16 Bs[128 * 64];   // 16 KB
  const int tid = threadIdx.x;
  const int w = tid >> 6, l = tid & 63;
  const int lr = l & 15, lq = l >> 4;
  const int m0 = blockIdx.y * 64, n0 = blockIdx.x * 128;
  const int wr = (w >> 1) * 32, wc = (w & 1) * 64;
  f32x4 acc[2][4] = {};
  for (int kt = 0; kt < K; kt += 64) {
#pragma unroll
    for (int i = 0; i < 2; ++i) {
      int c = (i * 4 + w) * 64 + l;
      LOADLDS16(A + (size_t)(m0 + (c >> 3)) * K + kt + (c & 7) * 8,
                As + (size_t)(i * 4 + w) * 512);
    }
#pragma unroll
    for (int i = 0; i < 4; ++i) {
      int c = (i * 4 + w) * 64 + l;
      LOADLDS16(Bt + (size_t)(n0 + (c >> 3)) * K + kt + (c & 7) * 8,
                Bs + (size_t)(i * 4 + w) * 512);
    }
    __syncthreads();
#pragma unroll
    for (int kk = 0; kk < 2; ++kk) {
      f16x8 af[2], bf[4];
#pragma unroll
      for (int m = 0; m < 2; ++m)
        af[m] = *reinterpret_cast<const f16x8*>(As + (wr + m * 16 + lr) * 64 + kk * 32 + lq * 8);
#pragma unroll
      for (int n = 0; n < 4; ++n)
        bf[n] = *reinterpret_cast<const f16x8*>(Bs + (wc + n * 16 + lr) * 64 + kk * 32 + lq * 8);
#pragma unroll
      for (int m = 0; m < 2; ++m)
#pragma unroll
        for (int n = 0; n < 4; ++n)
          acc[m][n] = __builtin_amdgcn_mfma_f32_16x16x32_f16(af[m], bf[n], acc[m][n], 0, 0, 0);
    }
    __syncthreads();
  }
#pragma unroll
  for (int m = 0; m < 2; ++m)
#pragma unroll
    for (int n = 0; n < 4; ++n)
#pragma unroll
      for (int r = 0; r < 4; ++r) {
        int row = m0 + wr + m * 16 + lq * 4 + r;
        int col = n0 + wc + n * 16 + lr;
        if (EPI == 0) {
          reinterpret_cast<float*>(out)[(size_t)row * N + col] = acc[m][n][r];
        } else {
          int b = row >> 10, s = row & 1023;
          int plane = col >> 10, cc = col & 1023;
          int h = cc >> 6, dh = cc & 63;
          reinterpret_cast<f16*>(out)[(size_t)plane * 4194304 +
                                      (((size_t)(b * 16 + h)) * 1024 + s) * 64 + dh] =
              (f16)acc[m][n][r];
        }
      }
}

// ---------------------------------------------------------------------------
// V transpose per head: vb[bh][1024][64] -> vtb[bh][64][1024]
// ---------------------------------------------------------------------------
__global__ __launch_bounds__(256) void k_vtrans(const f16* __restrict__ vb,
                                                f16* __restrict__ vtb) {
  const int bh = blockIdx.y, s0 = blockIdx.x * 64;
  __shared__ f16 T[64][72];  // [dh][sk]
  const int tid = threadIdx.x;
  const f16* src = vb + (size_t)bh * 1024 * 64;
#pragma unroll
  for (int i = 0; i < 2; ++i) {
    int c = i * 256 + tid;
    int row = c >> 3, co = (c & 7) * 8;
    f16x8 v = *reinterpret_cast<const f16x8*>(src + (size_t)(s0 + row) * 64 + co);
#pragma unroll
    for (int j = 0; j < 8; ++j) T[co + j][row] = v[j];
  }
  __syncthreads();
  f16* dst = vtb + (size_t)bh * 64 * 1024;
#pragma unroll
  for (int i = 0; i < 2; ++i) {
    int c = i * 256 + tid;
    int dh = c >> 3, so = (c & 7) * 8;
    f16x8 v;
#pragma unroll
    for (int j = 0; j < 8; ++j) v[j] = T[dh][so + j];
    *reinterpret_cast<f16x8*>(dst + (size_t)dh * 1024 + s0 + so) = v;
  }
}

// ---------------------------------------------------------------------------
// Fused flash attention (T5: scores = QK^T + bias, no 1/sqrt scale).
// 4 waves x 16 q-rows; KV tiles of 64, double-buffered, XOR-swizzled LDS.
// XCD-chunked grid: ord = (bid&7)*128 + bid>>3, h-major -> each XCD owns 2
// heads (bias slice fetched once per XCD; K/V/Q L2-resident, disjoint).
// One barrier per KV iteration; K/V prefetched into regs across it (T14).
// ---------------------------------------------------------------------------
__global__ __launch_bounds__(256, 4) void k_attn(const f16* __restrict__ qb,
                                                 const f16* __restrict__ kb,
                                                 const f16* __restrict__ vtb,
                                                 const float* __restrict__ bias,
                                                 f16* __restrict__ ctx) {
  const int bid = blockIdx.x;
  const int ord = (bid & 7) * 128 + (bid >> 3);
  const int h = ord >> 6, qt = (ord >> 2) & 15, b = ord & 3;
  const int bh = b * 16 + h;
  const int q0 = qt * 64;
  const int tid = threadIdx.x, w = tid >> 6, l = tid & 63;
  const int lr = l & 15, lq = l >> 4;

  // linear [64][64] f16 tiles, XOR-swizzled: elem = row*64 + (col ^ ((row&7)<<3))
  __shared__ f16 Ks[2][4096];
  __shared__ f16 Vs[2][4096];
  __shared__ f16 Ps[4][1024];  // per-wave [16][64], same swizzle

  const f16* qp = qb + ((size_t)bh * 1024 + q0 + w * 16 + lr) * 64 + lq * 8;
  f16x8 qf0 = *reinterpret_cast<const f16x8*>(qp);
  f16x8 qf1 = *reinterpret_cast<const f16x8*>(qp + 32);

  f32x4 O[4] = {};
  float mrun[4], lrun[4];
#pragma unroll
  for (int r = 0; r < 4; ++r) { mrun[r] = -3.0e38f; lrun[r] = 0.f; }

  const f16* kbase = kb + (size_t)bh * 1024 * 64;
  const f16* vbase = vtb + (size_t)bh * 64 * 1024;
  const float* bbase = bias + ((size_t)h * 1024 + q0 + w * 16) * 1024;

  const int row0 = tid >> 3, co = (tid & 7) * 8;

  // ---- prologue: stage tile 0 ----
#pragma unroll
  for (int i = 0; i < 2; ++i) {
    int row = row0 + i * 32;
    int sw = row * 64 + (co ^ ((row & 7) << 3));
    *reinterpret_cast<f16x8*>(&Ks[0][sw]) =
        *reinterpret_cast<const f16x8*>(kbase + (size_t)row * 64 + co);
    *reinterpret_cast<f16x8*>(&Vs[0][sw]) =
        *reinterpret_cast<const f16x8*>(vbase + (size_t)row * 1024 + co);
  }
  __syncthreads();

  for (int it = 0; it < 16; ++it) {
    const int cur = it & 1;
    // ---- (A) prefetch next K/V tile into regs (lands at end of body) ----
    f16x8 kreg[2], vreg[2];
    if (it < 15) {
      const f16* kn = kbase + (size_t)(it + 1) * 64 * 64;
      const f16* vn = vbase + (size_t)(it + 1) * 64;
#pragma unroll
      for (int i = 0; i < 2; ++i) {
        int row = row0 + i * 32;
        kreg[i] = *reinterpret_cast<const f16x8*>(kn + (size_t)row * 64 + co);
        vreg[i] = *reinterpret_cast<const f16x8*>(vn + (size_t)row * 1024 + co);
      }
    }
    // ---- (A2) bias loads for THIS tile (covered by ds_read+MFMA below) ----
    const float* bp = bbase + it * 64;
    float breg[16];
#pragma unroll
    for (int c = 0; c < 4; ++c)
#pragma unroll
      for (int r = 0; r < 4; ++r)
        breg[c * 4 + r] = bp[(size_t)(lq * 4 + r) * 1024 + c * 16 + lr];

    // ---- (B) S = Q K^T ----
    f32x4 S[4] = {};
#pragma unroll
    for (int c = 0; c < 4; ++c) {
      int row = c * 16 + lr;
      int base = row * 64, s8 = (row & 7) << 3;
      f16x8 kf0 = *reinterpret_cast<const f16x8*>(&Ks[cur][base + ((lq * 8) ^ s8)]);
      f16x8 kf1 = *reinterpret_cast<const f16x8*>(&Ks[cur][base + ((32 + lq * 8) ^ s8)]);
      S[c] = __builtin_amdgcn_mfma_f32_16x16x32_f16(qf0, kf0, S[c], 0, 0, 0);
      S[c] = __builtin_amdgcn_mfma_f32_16x16x32_f16(qf1, kf1, S[c], 0, 0, 0);
    }

    // ---- + position bias ----
#pragma unroll
    for (int c = 0; c < 4; ++c)
#pragma unroll
      for (int r = 0; r < 4; ++r) S[c][r] += breg[c * 4 + r];

    // ---- online softmax (row = lq*4+r; reduce over 16 lanes of lr) ----
    float tmax[4];
#pragma unroll
    for (int r = 0; r < 4; ++r)
      tmax[r] = fmaxf(fmaxf(S[0][r], S[1][r]), fmaxf(S[2][r], S[3][r]));
#pragma unroll
    for (int msk = 1; msk <= 8; msk <<= 1)
#pragma unroll
      for (int r = 0; r < 4; ++r)
        tmax[r] = fmaxf(tmax[r], __shfl_xor(tmax[r], msk, 64));
    float scale[4], rsum[4];
#pragma unroll
    for (int r = 0; r < 4; ++r) {
      float mnew = fmaxf(mrun[r], tmax[r]);
      scale[r] = __expf(mrun[r] - mnew);
      mrun[r] = mnew;
      rsum[r] = 0.f;
    }
#pragma unroll
    for (int c = 0; c < 4; ++c)
#pragma unroll
      for (int r = 0; r < 4; ++r) {
        float p = __expf(S[c][r] - mrun[r]);
        S[c][r] = p;
        rsum[r] += p;
      }
#pragma unroll
    for (int msk = 1; msk <= 8; msk <<= 1)
#pragma unroll
      for (int r = 0; r < 4; ++r) rsum[r] += __shfl_xor(rsum[r], msk, 64);
#pragma unroll
    for (int r = 0; r < 4; ++r) lrun[r] = lrun[r] * scale[r] + rsum[r];

    // ---- rescale O, spill P (wave-private; no barrier needed) ----
#pragma unroll
    for (int c = 0; c < 4; ++c)
#pragma unroll
      for (int r = 0; r < 4; ++r) {
        O[c][r] *= scale[r];
        int prow = lq * 4 + r;
        Ps[w][prow * 64 + ((c * 16 + lr) ^ ((prow & 7) << 3))] = (f16)S[c][r];
      }

    // ---- O += P @ V (lgkmcnt orders the wave-local P round-trip) ----
    {
      int s8p = (lr & 7) << 3;
      f16x8 pa0 = *reinterpret_cast<const f16x8*>(&Ps[w][lr * 64 + ((lq * 8) ^ s8p)]);
      f16x8 pa1 = *reinterpret_cast<const f16x8*>(&Ps[w][lr * 64 + ((32 + lq * 8) ^ s8p)]);
#pragma unroll
      for (int c = 0; c < 4; ++c) {
        int row = c * 16 + lr;
        int base = row * 64, s8 = (row & 7) << 3;
        f16x8 vf0 = *reinterpret_cast<const f16x8*>(&Vs[cur][base + ((lq * 8) ^ s8)]);
        f16x8 vf1 = *reinterpret_cast<const f16x8*>(&Vs[cur][base + ((32 + lq * 8) ^ s8)]);
        O[c] = __builtin_amdgcn_mfma_f32_16x16x32_f16(pa0, vf0, O[c], 0, 0, 0);
        O[c] = __builtin_amdgcn_mfma_f32_16x16x32_f16(pa1, vf1, O[c], 0, 0, 0);
      }
    }

    // ---- (C) commit prefetched tile to the other buffer ----
    if (it < 15) {
#pragma unroll
      for (int i = 0; i < 2; ++i) {
        int row = row0 + i * 32;
        int sw = row * 64 + (co ^ ((row & 7) << 3));
        *reinterpret_cast<f16x8*>(&Ks[cur ^ 1][sw]) = kreg[i];
        *reinterpret_cast<f16x8*>(&Vs[cur ^ 1][sw]) = vreg[i];
      }
    }
    __syncthreads();
  }

  // ---- epilogue: ctx[b][q][h*64+dh] f16 ----
#pragma unroll
  for (int c = 0; c < 4; ++c)
#pragma unroll
    for (int r = 0; r < 4; ++r) {
      float o = O[c][r] / lrun[r];
      int row = q0 + w * 16 + lq * 4 + r;
      ctx[((size_t)b * 1024 + row) * 1024 + h * 64 + c * 16 + lr] = (f16)o;
    }
}

// ---------------------------------------------------------------------------
extern "C" void kernel_launch(void* const* d_in, const int* in_sizes, int n_in,
                              void* d_out, int out_size, void* d_ws,
                              size_t ws_size, hipStream_t stream) {
  const float* input_ids = (const float*)d_in[0];
  const float* enc = (const float*)d_in[1];
  const float* bias = (const float*)d_in[2];
  const float* Wq = (const float*)d_in[3];
  const float* Wk = (const float*)d_in[4];
  const float* Wv = (const float*)d_in[5];
  const float* Wo = (const float*)d_in[6];

  char* ws = (char*)d_ws;
  const size_t MB = 1024 * 1024;
  f16* Xq  = (f16*)(ws + 0 * MB);   // 8 MB; dead after Q-proj -> reused as ctx
  f16* Xkv = (f16*)(ws + 8 * MB);   // 8 MB; dead after KV-proj -> reused as vtb
  f16* Wqt = (f16*)(ws + 16 * MB);  // 2 MB each; Wkt|Wvt contiguous = [2048][1024]
  f16* Wkt = (f16*)(ws + 18 * MB);
  f16* Wvt = (f16*)(ws + 20 * MB);
  f16* Wot = (f16*)(ws + 22 * MB);
  f16* qbuf = (f16*)(ws + 24 * MB); // 8 MB [bh][s][dh]
  f16* kbuf = (f16*)(ws + 32 * MB); // 8 MB; vbuf = kbuf + 4M elems (fused epi)
  f16* vbuf = (f16*)(ws + 40 * MB);
  f16* vtb = Xkv;   // [bh][dh][sk]
  f16* ctxb = Xq;   // [4096][1024]

  k_cast<<<4096, 256, 0, stream>>>(input_ids, Xq, 1048576);
  k_cast<<<4096, 256, 0, stream>>>(enc, Xkv, 1048576);
  k_castw_t<<<dim3(16, 16, 4), 256, 0, stream>>>(Wq, Wk, Wv, Wo, Wqt, Wkt, Wvt, Wot);

  k_gemm<1><<<dim3(8, 64), 256, 0, stream>>>(Xq, Wqt, (void*)qbuf, 4096, 1024, 1024);
  // fused K+V projection: Bt = [Wkt|Wvt] rows 0..2047, planes split in epilogue
  k_gemm<1><<<dim3(16, 64), 256, 0, stream>>>(Xkv, Wkt, (void*)kbuf, 4096, 2048, 1024);

  k_vtrans<<<dim3(16, 64), 256, 0, stream>>>(vbuf, vtb);

  k_attn<<<1024, 256, 0, stream>>>(qbuf, kbuf, vtb, bias, ctxb);

  k_gemm<0><<<dim3(8, 64), 256, 0, stream>>>(ctxb, Wot, d_out, 4096, 1024, 1024);
}